// Round 1
// baseline (896.643 us; speedup 1.0000x reference)
//
#include <hip/hip_runtime.h>
#include <hip/hip_bf16.h>
#include <math.h>

#define Hdim 512
#define Ndim 64
#define Ldim 2048
#define Bdim 8
#define HN (Hdim*Ndim)

// ---------------------------------------------------------------------------
// Stage A: per-(h,n) params: dtA_re, dtA_im, Ct_re, Ct_im into ws
// ---------------------------------------------------------------------------
__global__ __launch_bounds__(256) void prep_kernel(
    const float* __restrict__ C_ri, const float* __restrict__ log_dt,
    const float* __restrict__ A_ri, float* __restrict__ ws) {
  int idx = blockIdx.x * 256 + threadIdx.x;
  if (idx >= HN) return;
  int h = idx >> 6;
  int n = idx & 63;
  float dt = expf(log_dt[h]);
  float ar = A_ri[2 * n], ai = A_ri[2 * n + 1];
  float dre = dt * ar, dim = dt * ai;
  float er = expf(dre);
  float s, c;
  sincosf(dim, &s, &c);
  float em1r = er * c - 1.0f;
  float em1i = er * s;
  float cr = C_ri[2 * idx], ci = C_ri[2 * idx + 1];
  // Ct = C * (exp(dtA)-1) / A
  float numr = cr * em1r - ci * em1i;
  float numi = cr * em1i + ci * em1r;
  float den = ar * ar + ai * ai;
  ws[idx]           = dre;
  ws[HN + idx]      = dim;
  ws[2 * HN + idx]  = (numr * ar + numi * ai) / den;
  ws[3 * HN + idx]  = (numi * ar - numr * ai) / den;
}

// ---------------------------------------------------------------------------
// Stage B: k[h,l] = 2 * sum_n ( Ctr*exp(x)cos(th) - Cti*exp(x)sin(th) )
// phase rounded to f32 exactly like the reference, then reduced in double.
// ---------------------------------------------------------------------------
__global__ __launch_bounds__(256) void kgen_kernel(const float* __restrict__ ws,
                                                   float* __restrict__ kout) {
  __shared__ float sre[64], sim[64], scr[64], sci[64];
  int h = blockIdx.y;
  int tid = threadIdx.x;
  if (tid < 64) {
    sre[tid] = ws[h * 64 + tid];
    sim[tid] = ws[HN + h * 64 + tid];
    scr[tid] = ws[2 * HN + h * 64 + tid];
    sci[tid] = ws[3 * HN + h * 64 + tid];
  }
  __syncthreads();
  int l = blockIdx.x * 256 + tid;
  float lf = (float)l;
  const double TWO_PI = 6.283185307179586476925286766559;
  const double INV_TWO_PI = 0.15915494309189533576888376337251;
  float acc = 0.0f;
  for (int n = 0; n < 64; ++n) {
    float r = expf(sre[n] * lf);
    float thf = sim[n] * lf;          // f32-rounded phase, matches reference
    double th = (double)thf;
    th -= floor(th * INV_TWO_PI) * TWO_PI;  // exact-ish reduction of that value
    float s, c;
    sincosf((float)th, &s, &c);
    acc = fmaf(scr[n], r * c, acc);
    acc = fmaf(-sci[n], r * s, acc);
  }
  kout[(size_t)h * Ldim + l] = 2.0f * acc;
}

// ---------------------------------------------------------------------------
// Stage C: causal conv y[t] = sum_{s<=t} k[t-s] u[s], fused  y += D*u, gelu.
// One block per (b,h) row. k row staged in LDS once; u per 256-tile.
// Each thread: 8 consecutive outputs, modular sliding window of k in regs.
// ---------------------------------------------------------------------------
__global__ __launch_bounds__(256) void conv_kernel(
    const float* __restrict__ u, const float* __restrict__ kker,
    const float* __restrict__ Dv, float* __restrict__ gy) {
  __shared__ __align__(16) float kl[Ldim];
  __shared__ float ul[256];
  int row = blockIdx.x;           // b*H + h
  int h = row & (Hdim - 1);
  int tid = threadIdx.x;
  const float* krow = kker + (size_t)h * Ldim;
  for (int i = tid; i < Ldim / 4; i += 256)
    ((float4*)kl)[i] = ((const float4*)krow)[i];
  const float* urow = u + (size_t)row * Ldim;
  int t0 = tid << 3;                      // first output index of this thread
  int wave_tmax = ((tid >> 6) << 9) + 511;  // max t in this wave
  float acc[8] = {0, 0, 0, 0, 0, 0, 0, 0};
  for (int s0 = 0; s0 < Ldim; s0 += 256) {
    __syncthreads();
    ul[tid] = urow[s0 + tid];
    __syncthreads();
    if (s0 <= wave_tmax) {                // wave-uniform triangle skip
      int kbase = t0 - s0;
      float r[8];
      r[0] = 0.0f;
#pragma unroll
      for (int x = 1; x < 8; ++x) {
        int idx = kbase + x;
        float v = kl[idx < 0 ? 0 : idx];
        r[x] = (idx < 0) ? 0.0f : v;
      }
      for (int jb = 0; jb < 256; jb += 8) {
#pragma unroll
        for (int m = 0; m < 8; ++m) {
          int idx = kbase - jb - m;
          float v = kl[idx < 0 ? 0 : idx];
          r[(8 - m) & 7] = (idx < 0) ? 0.0f : v;   // slot (-j)&7, j=jb+m
          float uj = ul[jb + m];
#pragma unroll
          for (int i = 0; i < 8; ++i)
            acc[i] = fmaf(r[(i - m) & 7], uj, acc[i]);
        }
      }
    }
  }
  // fused skip + exact gelu
  float dh = Dv[h];
  float4 o4[2];
  float* op = (float*)o4;
#pragma unroll
  for (int i = 0; i < 8; ++i) {
    float yv = fmaf(dh, urow[t0 + i], acc[i]);
    op[i] = 0.5f * yv * (1.0f + erff(yv * 0.70710678118654752f));
  }
  float* yrow = gy + (size_t)row * Ldim + t0;
  *(float4*)yrow = o4[0];
  *(float4*)(yrow + 4) = o4[1];
}

// ---------------------------------------------------------------------------
// Stage D: z = W @ gy + b ; out = z[:512] * sigmoid(z[512:])
// 64(o) x 64(l) tile per block, K=512 in steps of 16, 4x4 micro-tile, both
// halves of W accumulated simultaneously.
// ---------------------------------------------------------------------------
__global__ __launch_bounds__(256) void glu_kernel(
    const float* __restrict__ gy, const float* __restrict__ W,
    const float* __restrict__ bias, float* __restrict__ out) {
  __shared__ __align__(16) float wa[16][64];
  __shared__ __align__(16) float wg[16][64];
  __shared__ __align__(16) float gl[16][64];
  int b = blockIdx.z;
  int o0 = blockIdx.y << 6;
  int l0 = blockIdx.x << 6;
  int tid = threadIdx.x;
  int ty = tid >> 4, tx = tid & 15;
  float accA[4][4] = {{0.f}}, accG[4][4] = {{0.f}};
  int o_st = tid & 63, k4 = (tid >> 6) << 2;
  int kk_st = tid & 15, lq = (tid >> 4) << 2;
  for (int h0 = 0; h0 < Hdim; h0 += 16) {
    __syncthreads();
    float4 va = *(const float4*)&W[(size_t)(o0 + o_st) * Hdim + h0 + k4];
    wa[k4 + 0][o_st] = va.x; wa[k4 + 1][o_st] = va.y;
    wa[k4 + 2][o_st] = va.z; wa[k4 + 3][o_st] = va.w;
    float4 vg = *(const float4*)&W[(size_t)(Hdim + o0 + o_st) * Hdim + h0 + k4];
    wg[k4 + 0][o_st] = vg.x; wg[k4 + 1][o_st] = vg.y;
    wg[k4 + 2][o_st] = vg.z; wg[k4 + 3][o_st] = vg.w;
    *(float4*)&gl[kk_st][lq] =
        *(const float4*)&gy[((size_t)(b * Hdim + h0 + kk_st)) * Ldim + l0 + lq];
    __syncthreads();
#pragma unroll
    for (int kk = 0; kk < 16; ++kk) {
      float4 a4 = *(const float4*)&wa[kk][ty << 2];
      float4 g4 = *(const float4*)&wg[kk][ty << 2];
      float4 y4 = *(const float4*)&gl[kk][tx << 2];
      float av[4] = {a4.x, a4.y, a4.z, a4.w};
      float gv[4] = {g4.x, g4.y, g4.z, g4.w};
      float yv[4] = {y4.x, y4.y, y4.z, y4.w};
#pragma unroll
      for (int i = 0; i < 4; ++i)
#pragma unroll
        for (int j = 0; j < 4; ++j) {
          accA[i][j] = fmaf(av[i], yv[j], accA[i][j]);
          accG[i][j] = fmaf(gv[i], yv[j], accG[i][j]);
        }
    }
  }
#pragma unroll
  for (int i = 0; i < 4; ++i) {
    int o = o0 + (ty << 2) + i;
    float ba = bias[o], bg = bias[Hdim + o];
    float4 res;
    float* rp = (float*)&res;
#pragma unroll
    for (int j = 0; j < 4; ++j) {
      float a = accA[i][j] + ba;
      float g = accG[i][j] + bg;
      rp[j] = a * (1.0f / (1.0f + expf(-g)));
    }
    *(float4*)&out[((size_t)(b * Hdim + o)) * Ldim + l0 + (tx << 2)] = res;
  }
}

// ---------------------------------------------------------------------------
extern "C" void kernel_launch(void* const* d_in, const int* in_sizes, int n_in,
                              void* d_out, int out_size, void* d_ws,
                              size_t ws_size, hipStream_t stream) {
  const float* u      = (const float*)d_in[0];
  const float* C_ri   = (const float*)d_in[1];
  const float* log_dt = (const float*)d_in[2];
  const float* D      = (const float*)d_in[3];
  const float* W      = (const float*)d_in[4];
  const float* bias   = (const float*)d_in[5];
  const float* A_ri   = (const float*)d_in[6];
  float* out = (float*)d_out;
  float* ws  = (float*)d_ws;
  float* kbuf = ws + 4 * HN;                 // H*L floats
  float* gy   = kbuf + (size_t)Hdim * Ldim;  // B*H*L floats

  prep_kernel<<<HN / 256, 256, 0, stream>>>(C_ri, log_dt, A_ri, ws);
  kgen_kernel<<<dim3(Ldim / 256, Hdim), 256, 0, stream>>>(ws, kbuf);
  conv_kernel<<<Bdim * Hdim, 256, 0, stream>>>(u, kbuf, D, gy);
  glu_kernel<<<dim3(Ldim / 64, Hdim / 64, Bdim), 256, 0, stream>>>(gy, W, bias, out);
}

// Round 2
// 112.302 us; speedup vs baseline: 7.9842x; 7.9842x over previous
//
#include <hip/hip_runtime.h>
#include <math.h>

#define Hh 512
#define Nn 64
#define Ll 2048
#define Bb 8

typedef float f32x4 __attribute__((ext_vector_type(4)));
typedef __bf16 bf16x8 __attribute__((ext_vector_type(8)));

__device__ __forceinline__ unsigned short f2b(float x) {
  unsigned u = __builtin_bit_cast(unsigned, x);
  u += 0x7FFFu + ((u >> 16) & 1u);
  return (unsigned short)(u >> 16);
}
__device__ __forceinline__ float b2f(unsigned short b) {
  unsigned u = ((unsigned)b) << 16;
  return __builtin_bit_cast(float, u);
}

union BF8 {
  unsigned short us[8];
  bf16x8 v;
  uint4 q;
};

// ---------------------------------------------------------------------------
// prep: per h, per n: lambda = exp(dtA); write
//   A1[h][128][64]  bf16 : rows 2n=Re(P), 2n+1=Im(P); P[n][q]=lambda^(63-q)
//   A2[h][64][192]  bf16 : cols 0..63 = T (Toeplitz of kQ), 64+2n=2Re(Ct*l^(t+1)),
//                          64+2n+1 = -2Im(Ct*l^(t+1))
//   lamQ[h][128]    f32  : (Re,Im) of lambda^64
// ---------------------------------------------------------------------------
__global__ __launch_bounds__(64) void prep_kernel(
    const float* __restrict__ C_ri, const float* __restrict__ log_dt,
    const float* __restrict__ A_ri, unsigned short* __restrict__ A1,
    unsigned short* __restrict__ A2, float* __restrict__ lamQ) {
  int h = blockIdx.x;
  int n = threadIdx.x;
  float dt = expf(log_dt[h]);
  float ar = A_ri[2 * n], ai = A_ri[2 * n + 1];
  float dre = dt * ar, dim = dt * ai;
  float er = expf(dre);
  float sn, cs;
  sincosf(dim, &sn, &cs);
  float lr = er * cs, li = er * sn;
  // Ct = C * (exp(dtA)-1)/A
  float em1r = lr - 1.0f, em1i = li;
  float cr = C_ri[(h * 64 + n) * 2], ci = C_ri[(h * 64 + n) * 2 + 1];
  float numr = cr * em1r - ci * em1i;
  float numi = cr * em1i + ci * em1r;
  float den = ar * ar + ai * ai;
  float ctr = (numr * ar + numi * ai) / den;
  float cti = (numi * ar - numr * ai) / den;
  // P rows (descending q)
  unsigned short* a1r = A1 + ((size_t)h * 128 + 2 * n) * 64;
  unsigned short* a1i = a1r + 64;
  float pr = 1.0f, pi = 0.0f;
  for (int q = 63; q >= 0; --q) {
    a1r[q] = f2b(pr);
    a1i[q] = f2b(pi);
    float t = pr * lr - pi * li;
    pi = pr * li + pi * lr;
    pr = t;
  }
  // lambda^64 by squaring
  float qr = lr, qi = li;
#pragma unroll
  for (int s = 0; s < 6; ++s) {
    float t = qr * qr - qi * qi;
    qi = 2.0f * qr * qi;
    qr = t;
  }
  lamQ[h * 128 + 2 * n] = qr;
  lamQ[h * 128 + 2 * n + 1] = qi;
  // W2: w = 2*Ct*lambda^(tau+1)
  float wr = 2.0f * (ctr * lr - cti * li);
  float wi = 2.0f * (ctr * li + cti * lr);
  for (int t = 0; t < 64; ++t) {
    A2[((size_t)h * 64 + t) * 192 + 64 + 2 * n] = f2b(wr);
    A2[((size_t)h * 64 + t) * 192 + 64 + 2 * n + 1] = f2b(-wi);
    float tmp = wr * lr - wi * li;
    wi = wr * li + wi * lr;
    wr = tmp;
  }
  // kQ[l] = 2*Re(sum_n Ct*lambda^l), l<64, then T[tau][q] = kQ[tau-q]
  __shared__ float kt[64][65];
  __shared__ float kqs[64];
  float tr = ctr, ti = cti;
  for (int l = 0; l < 64; ++l) {
    kt[l][n] = tr;
    float tmp = tr * lr - ti * li;
    ti = tr * li + ti * lr;
    tr = tmp;
  }
  __syncthreads();
  float s = 0.0f;
  for (int j = 0; j < 64; ++j) s += kt[n][j];
  kqs[n] = 2.0f * s;
  __syncthreads();
  int tau = n;
  for (int q = 0; q < 64; ++q)
    A2[((size_t)h * 64 + tau) * 192 + q] = (q <= tau) ? f2b(kqs[tau - q]) : 0;
}

// ---------------------------------------------------------------------------
// W -> bf16
// ---------------------------------------------------------------------------
__global__ __launch_bounds__(256) void wcvt_kernel(const float* __restrict__ W,
                                                   unsigned short* __restrict__ Wbf) {
  int i = (blockIdx.x * 256 + threadIdx.x) * 8;
  float4 a = *(const float4*)(W + i);
  float4 b = *(const float4*)(W + i + 4);
  BF8 o;
  o.us[0] = f2b(a.x); o.us[1] = f2b(a.y); o.us[2] = f2b(a.z); o.us[3] = f2b(a.w);
  o.us[4] = f2b(b.x); o.us[5] = f2b(b.y); o.us[6] = f2b(b.z); o.us[7] = f2b(b.w);
  *(uint4*)(Wbf + i) = o.q;
}

__device__ __forceinline__ bf16x8 cvt8(const float* p) {
  float4 a = *(const float4*)p;
  float4 b = *(const float4*)(p + 4);
  BF8 o;
  o.us[0] = f2b(a.x); o.us[1] = f2b(a.y); o.us[2] = f2b(a.z); o.us[3] = f2b(a.w);
  o.us[4] = f2b(b.x); o.us[5] = f2b(b.y); o.us[6] = f2b(b.z); o.us[7] = f2b(b.w);
  return o.v;
}

// ---------------------------------------------------------------------------
// fused conv: per (col-half, h).  GEMM1 S=P*u -> LDS, complex recurrence ->
// Xprev in LDS, GEMM2 [T|W2]*[u;X] + D*u + gelu -> gy (bf16, [b][h][l])
// ---------------------------------------------------------------------------
__global__ __launch_bounds__(256) void fused_conv_kernel(
    const float* __restrict__ u, const unsigned short* __restrict__ A1,
    const unsigned short* __restrict__ A2, const float* __restrict__ lamQ,
    const float* __restrict__ Dv, unsigned short* __restrict__ gy) {
  __shared__ unsigned short Sl[128 * 128];  // S^T[bc][n2], later gy[bc][tau]
  __shared__ unsigned short Xl[128 * 128];  // Xprev[bc][n2]
  char* Sb = (char*)Sl;
  char* Xb = (char*)Xl;
  int h = blockIdx.y;
  int bs = blockIdx.x * 4;  // first batch of this col-half
  int tid = threadIdx.x;
  int w = tid >> 6, lane = tid & 63, lg = lane >> 4, l15 = lane & 15;

  // ---- GEMM1: M=128 (8 mtiles, wave w -> 2w,2w+1), K=64, N=128
  bf16x8 a1f[2][2];
#pragma unroll
  for (int i = 0; i < 2; ++i) {
    int row = (2 * w + i) * 16 + l15;
#pragma unroll
    for (int kb = 0; kb < 2; ++kb)
      a1f[i][kb] = *(const bf16x8*)(A1 + ((size_t)h * 128 + row) * 64 + kb * 32 + lg * 8);
  }
#pragma unroll
  for (int ct = 0; ct < 8; ++ct) {
    int bc = ct * 16 + l15;
    int b = bs + (bc >> 5), c = bc & 31;
    const float* up = u + ((size_t)(b * Hh + h)) * Ll + c * 64;
    bf16x8 bfr[2];
#pragma unroll
    for (int kb = 0; kb < 2; ++kb) bfr[kb] = cvt8(up + kb * 32 + lg * 8);
#pragma unroll
    for (int i = 0; i < 2; ++i) {
      f32x4 acc = {0.f, 0.f, 0.f, 0.f};
      acc = __builtin_amdgcn_mfma_f32_16x16x32_bf16(a1f[i][0], bfr[0], acc, 0, 0, 0);
      acc = __builtin_amdgcn_mfma_f32_16x16x32_bf16(a1f[i][1], bfr[1], acc, 0, 0, 0);
      int n2q = (2 * w + i) * 16 + lg * 4;
      uint2 pk;
      pk.x = f2b(acc[0]) | ((unsigned)f2b(acc[1]) << 16);
      pk.y = f2b(acc[2]) | ((unsigned)f2b(acc[3]) << 16);
      int byte = (bc * 256 + n2q * 2) ^ ((bc & 7) << 4);
      *(uint2*)(Sb + byte) = pk;
    }
  }
  __syncthreads();

  // ---- recurrence: thread = (n in 0..63, bloc in 0..3)
  {
    int n = tid & 63, bloc = tid >> 6;
    float lqr = lamQ[h * 128 + 2 * n], lqi = lamQ[h * 128 + 2 * n + 1];
    float Xr = 0.f, Xi = 0.f;
    for (int c = 0; c < 32; ++c) {
      int bc = bloc * 32 + c;
      int byte = (bc * 256 + 4 * n) ^ ((bc & 7) << 4);
      unsigned px = (unsigned)f2b(Xr) | ((unsigned)f2b(Xi) << 16);
      *(unsigned*)(Xb + byte) = px;
      unsigned ps = *(const unsigned*)(Sb + byte);
      float Sr = b2f((unsigned short)(ps & 0xFFFF));
      float Si = b2f((unsigned short)(ps >> 16));
      float nXr = lqr * Xr - lqi * Xi + Sr;
      float nXi = lqr * Xi + lqi * Xr + Si;
      Xr = nXr;
      Xi = nXi;
    }
  }
  __syncthreads();

  // ---- GEMM2: M=64 (wave w -> mtile w), K=192, N=128; epilogue fused
  bf16x8 a2f[6];
  int rowA = w * 16 + l15;
#pragma unroll
  for (int kb = 0; kb < 6; ++kb)
    a2f[kb] = *(const bf16x8*)(A2 + ((size_t)h * 64 + rowA) * 192 + kb * 32 + lg * 8);
  float Dh = Dv[h];
#pragma unroll
  for (int ct = 0; ct < 8; ++ct) {
    int bc = ct * 16 + l15;
    int b = bs + (bc >> 5), c = bc & 31;
    const float* up = u + ((size_t)(b * Hh + h)) * Ll + c * 64;
    f32x4 acc = {0.f, 0.f, 0.f, 0.f};
#pragma unroll
    for (int kb = 0; kb < 2; ++kb) {
      bf16x8 bfr = cvt8(up + kb * 32 + lg * 8);
      acc = __builtin_amdgcn_mfma_f32_16x16x32_bf16(a2f[kb], bfr, acc, 0, 0, 0);
    }
#pragma unroll
    for (int kb = 2; kb < 6; ++kb) {
      int k2 = (kb - 2) * 32 + lg * 8;
      int byte = (bc * 256 + k2 * 2) ^ ((bc & 7) << 4);
      bf16x8 bx = *(const bf16x8*)(Xb + byte);
      acc = __builtin_amdgcn_mfma_f32_16x16x32_bf16(a2f[kb], bx, acc, 0, 0, 0);
    }
    int t0 = w * 16 + lg * 4;
    float4 uv = *(const float4*)(up + t0);
    const float* uvp = (const float*)&uv;
    unsigned short e[4];
#pragma unroll
    for (int r = 0; r < 4; ++r) {
      float y = acc[r] + Dh * uvp[r];
      float g = 0.5f * y * (1.0f + erff(y * 0.70710678118654752f));
      e[r] = f2b(g);
    }
    uint2 pk;
    pk.x = e[0] | ((unsigned)e[1] << 16);
    pk.y = e[2] | ((unsigned)e[3] << 16);
    int byte = (bc * 128 + t0 * 2) ^ ((bc & 7) << 4);
    *(uint2*)(Sb + byte) = pk;
  }
  __syncthreads();

  // ---- copy out gy (bf16, [b][h][l])
#pragma unroll
  for (int i = 0; i < 4; ++i) {
    int j = tid + 256 * i;
    int row = j >> 3, t8 = (j & 7) * 8;
    int byte = (row * 128 + t8 * 2) ^ ((row & 7) << 4);
    uint4 v = *(const uint4*)(Sb + byte);
    int b = bs + (row >> 5), c = row & 31;
    *(uint4*)(gy + ((size_t)(b * Hh + h)) * Ll + c * 64 + t8) = v;
  }
}

// ---------------------------------------------------------------------------
// GLU: z = Wbf @ gy + bias; out = a * sigmoid(g).  M-tile 64 (both halves),
// N-tile 128, K=512 in steps of 64 via pair-packed transposed LDS.
// ---------------------------------------------------------------------------
__global__ __launch_bounds__(256) void glu_kernel(
    const unsigned short* __restrict__ gy, const unsigned short* __restrict__ Wbf,
    const float* __restrict__ bias, float* __restrict__ out) {
  __shared__ unsigned int Pl[128 * 32];  // [row l][pair p], swizzled
  int b = blockIdx.z;
  int o0 = blockIdx.y * 64;
  int l0 = blockIdx.x * 128;
  int tid = threadIdx.x;
  int w = tid >> 6, lane = tid & 63, lg = lane >> 4, l15 = lane & 15;
  f32x4 accA[8], accG[8];
#pragma unroll
  for (int ct = 0; ct < 8; ++ct) {
    accA[ct] = (f32x4){0.f, 0.f, 0.f, 0.f};
    accG[ct] = (f32x4){0.f, 0.f, 0.f, 0.f};
  }
  int aro = o0 + w * 16 + l15;
  const unsigned short* wa = Wbf + (size_t)aro * 512;
  const unsigned short* wg = Wbf + (size_t)(Hh + aro) * 512;
  for (int h0 = 0; h0 < Hh; h0 += 64) {
    // stage gy tile, pair-packed + transposed
#pragma unroll
    for (int i = 0; i < 2; ++i) {
      int id = tid + 256 * i;
      int p = id >> 4, cg = id & 15;
      const unsigned short* g0 =
          gy + ((size_t)(b * Hh) + h0 + 2 * p) * Ll + l0 + cg * 8;
      BF8 r0, r1;
      r0.q = *(const uint4*)g0;
      r1.q = *(const uint4*)(g0 + Ll);
#pragma unroll
      for (int j = 0; j < 8; ++j) {
        int row = cg * 8 + j;
        int slot = (p >> 2) ^ ((row ^ (row >> 3)) & 7);
        Pl[row * 32 + slot * 4 + (p & 3)] =
            (unsigned)r0.us[j] | ((unsigned)r1.us[j] << 16);
      }
    }
    __syncthreads();
    bf16x8 aA[2], aG[2];
#pragma unroll
    for (int kb = 0; kb < 2; ++kb) {
      aA[kb] = *(const bf16x8*)(wa + h0 + kb * 32 + lg * 8);
      aG[kb] = *(const bf16x8*)(wg + h0 + kb * 32 + lg * 8);
    }
#pragma unroll
    for (int ct = 0; ct < 8; ++ct) {
      int rowB = ct * 16 + l15;
      int sw = (rowB ^ (rowB >> 3)) & 7;
#pragma unroll
      for (int kb = 0; kb < 2; ++kb) {
        int pb = kb * 4 + lg;
        int slot = pb ^ sw;
        bf16x8 bv = *(const bf16x8*)((const char*)Pl + rowB * 128 + slot * 16);
        accA[ct] = __builtin_amdgcn_mfma_f32_16x16x32_bf16(aA[kb], bv, accA[ct], 0, 0, 0);
        accG[ct] = __builtin_amdgcn_mfma_f32_16x16x32_bf16(aG[kb], bv, accG[ct], 0, 0, 0);
      }
    }
    __syncthreads();
  }
  // epilogue
#pragma unroll
  for (int ct = 0; ct < 8; ++ct) {
    int col = l0 + ct * 16 + l15;
#pragma unroll
    for (int r = 0; r < 4; ++r) {
      int o = o0 + w * 16 + lg * 4 + r;
      float a = accA[ct][r] + bias[o];
      float g = accG[ct][r] + bias[Hh + o];
      out[((size_t)(b * Hh + o)) * Ll + col] = a * (1.0f / (1.0f + expf(-g)));
    }
  }
}

// ---------------------------------------------------------------------------
extern "C" void kernel_launch(void* const* d_in, const int* in_sizes, int n_in,
                              void* d_out, int out_size, void* d_ws,
                              size_t ws_size, hipStream_t stream) {
  const float* u      = (const float*)d_in[0];
  const float* C_ri   = (const float*)d_in[1];
  const float* log_dt = (const float*)d_in[2];
  const float* Dv     = (const float*)d_in[3];
  const float* W      = (const float*)d_in[4];
  const float* bias   = (const float*)d_in[5];
  const float* A_ri   = (const float*)d_in[6];
  float* out = (float*)d_out;

  char* ws = (char*)d_ws;
  unsigned short* A1   = (unsigned short*)ws;                    // 512*128*64*2   = 8 MB
  unsigned short* A2   = (unsigned short*)(ws + 8388608);        // 512*64*192*2   = 12 MB
  float*          lamQ = (float*)(ws + 8388608 + 12582912);      // 512*128*4
  unsigned short* Wbf  = (unsigned short*)(ws + 8388608 + 12582912 + 262144);  // 1 MB
  unsigned short* gy   = (unsigned short*)(ws + 8388608 + 12582912 + 262144 + 1048576);  // 16 MB

  prep_kernel<<<Hh, 64, 0, stream>>>(C_ri, log_dt, A_ri, A1, A2, lamQ);
  wcvt_kernel<<<(2 * Hh * Hh) / (256 * 8), 256, 0, stream>>>(W, Wbf);
  fused_conv_kernel<<<dim3(2, Hh), 256, 0, stream>>>(u, A1, A2, lamQ, Dv, gy);
  glu_kernel<<<dim3(Ll / 128, Hh / 64, Bb), 256, 0, stream>>>(gy, Wbf, bias, out);
}

// Round 3
// 80.313 us; speedup vs baseline: 11.1643x; 1.3983x over previous
//
#include <hip/hip_runtime.h>
#include <math.h>

#define Hh 512
#define Nn 64
#define Ll 2048
#define Bb 8

typedef float f32x4 __attribute__((ext_vector_type(4)));
typedef __bf16 bf16x8 __attribute__((ext_vector_type(8)));

__device__ __forceinline__ unsigned short f2b(float x) {
  unsigned u = __builtin_bit_cast(unsigned, x);
  u += 0x7FFFu + ((u >> 16) & 1u);
  return (unsigned short)(u >> 16);
}
__device__ __forceinline__ float b2f(unsigned short b) {
  unsigned u = ((unsigned)b) << 16;
  return __builtin_bit_cast(float, u);
}

union BF8 {
  unsigned short us[8];
  bf16x8 v;
  uint4 q;
};

__device__ __forceinline__ uint4 cvt8q(const float* p) {
  float4 a = *(const float4*)p;
  float4 b = *(const float4*)(p + 4);
  BF8 o;
  o.us[0] = f2b(a.x); o.us[1] = f2b(a.y); o.us[2] = f2b(a.z); o.us[3] = f2b(a.w);
  o.us[4] = f2b(b.x); o.us[5] = f2b(b.y); o.us[6] = f2b(b.z); o.us[7] = f2b(b.w);
  return o.q;
}

// gelu tanh-form: y * sigmoid(1.5957691216*(y + 0.044715*y^3)); |err| < 5e-4
__device__ __forceinline__ float gelu_f(float y) {
  float t = y * y;
  float p = y * fmaf(0.0713548162726f, t, 1.59576912161f);
  float e = __expf(-p);
  return y / (1.0f + e);
}

// ---------------------------------------------------------------------------
// prep: per h: A1[h][128][64] bf16 (rows 2n=Re(P),2n+1=Im(P), P[n][q]=lam^(63-q));
// A2[h][64][256] bf16 (cols 0..63 = T Toeplitz, 64+2n / 64+2n+1 = +-2*Ct*lam^(t+1));
// lamQ[h][128] f32 = lambda^64.  All staged in swizzled LDS, coalesced copy-out.
// ---------------------------------------------------------------------------
__global__ __launch_bounds__(64) void prep_kernel(
    const float* __restrict__ C_ri, const float* __restrict__ log_dt,
    const float* __restrict__ A_ri, unsigned short* __restrict__ A1,
    unsigned short* __restrict__ A2, float* __restrict__ lamQ) {
  __shared__ char sm[16384 + 32768];
  __shared__ float kqs[64];
  float* kt = (float*)sm;        // 64x64 f32, overlaid with A1 region
  char* A1s = sm;                // 128 rows x 128B, swz ^((row&7)<<4)
  char* A2s = sm + 16384;        // 64 rows x 512B,  swz ^((row&7)<<4)
  int h = blockIdx.x, n = threadIdx.x;

  float dt = expf(log_dt[h]);
  float ar = A_ri[2 * n], ai = A_ri[2 * n + 1];
  float dre = dt * ar, dim = dt * ai;
  float er = expf(dre);
  float sn, cs;
  sincosf(dim, &sn, &cs);
  float lr = er * cs, li = er * sn;
  float em1r = lr - 1.0f, em1i = li;
  float cr = C_ri[(h * 64 + n) * 2], ci = C_ri[(h * 64 + n) * 2 + 1];
  float numr = cr * em1r - ci * em1i;
  float numi = cr * em1i + ci * em1r;
  float den = ar * ar + ai * ai;
  float ctr = (numr * ar + numi * ai) / den;
  float cti = (numi * ar - numr * ai) / den;
  // lambda^64 by squaring
  float qr = lr, qi = li;
#pragma unroll
  for (int s = 0; s < 6; ++s) {
    float t = qr * qr - qi * qi;
    qi = 2.0f * qr * qi;
    qr = t;
  }
  lamQ[h * 128 + 2 * n] = qr;
  lamQ[h * 128 + 2 * n + 1] = qi;
  // kt[l][n] = Re(Ct * lam^l), conflict-free writes; rotated reads
  float tr = ctr, ti = cti;
  for (int l = 0; l < 64; ++l) {
    kt[l * 64 + n] = tr;
    float t = tr * lr - ti * li;
    ti = tr * li + ti * lr;
    tr = t;
  }
  __syncthreads();
  float s = 0.0f;
  for (int j = 0; j < 64; ++j) s += kt[n * 64 + ((j + n) & 63)];
  kqs[n] = 2.0f * s;
  __syncthreads();  // done with kt region; reuse as A1s
  // P rows
  float pr = 1.0f, pi = 0.0f;
  for (int q = 63; q >= 0; --q) {
    *(unsigned short*)(A1s + ((((2 * n) * 128) + 2 * q) ^ (((2 * n) & 7) << 4))) = f2b(pr);
    *(unsigned short*)(A1s + ((((2 * n + 1) * 128) + 2 * q) ^ (((2 * n + 1) & 7) << 4))) = f2b(pi);
    float t = pr * lr - pi * li;
    pi = pr * li + pi * lr;
    pr = t;
  }
  // W2 columns 64+2n, 64+2n+1 (packed u32 per row)
  float wr = 2.0f * (ctr * lr - cti * li);
  float wi = 2.0f * (ctr * li + cti * lr);
  for (int t = 0; t < 64; ++t) {
    unsigned px = (unsigned)f2b(wr) | ((unsigned)f2b(-wi) << 16);
    *(unsigned*)(A2s + ((t * 512 + 128 + 4 * n) ^ ((t & 7) << 4))) = px;
    float tm = wr * lr - wi * li;
    wi = wr * li + wi * lr;
    wr = tm;
  }
  // T row tau=n: T[tau][q] = kQ[tau-q] (q<=tau)
  {
    int tau = n;
    for (int q0 = 0; q0 < 64; q0 += 8) {
      BF8 o;
#pragma unroll
      for (int j = 0; j < 8; ++j) {
        int q = q0 + j;
        o.us[j] = (q <= tau) ? f2b(kqs[tau - q]) : (unsigned short)0;
      }
      *(uint4*)(A2s + ((tau * 512 + 2 * q0) ^ ((tau & 7) << 4))) = o.q;
    }
  }
  __syncthreads();
  // coalesced copy-out
#pragma unroll
  for (int i = 0; i < 16; ++i) {
    int byte = (i * 64 + n) * 16;
    int row = byte >> 7;
    uint4 v = *(const uint4*)(A1s + (byte ^ ((row & 7) << 4)));
    *(uint4*)((char*)A1 + (size_t)h * 16384 + byte) = v;
  }
#pragma unroll
  for (int i = 0; i < 32; ++i) {
    int idx = i * 64 + n;
    int row = idx >> 5, u16o = idx & 31;
    int byte = row * 512 + u16o * 16;
    uint4 v = *(const uint4*)(A2s + (byte ^ ((row & 7) << 4)));
    *(uint4*)((char*)A2 + (size_t)h * 32768 + byte) = v;
  }
}

// ---------------------------------------------------------------------------
__global__ __launch_bounds__(256) void wcvt_kernel(const float* __restrict__ W,
                                                   unsigned short* __restrict__ Wbf) {
  int i = (blockIdx.x * 256 + threadIdx.x) * 8;
  *(uint4*)(Wbf + i) = cvt8q(W + i);
}

// ---------------------------------------------------------------------------
// fused conv: block = (col-quarter: 2 batches, h). u staged once to bf16 LDS;
// GEMM1 S=P*u -> Sb; recurrence -> Xb; GEMM2 [T|W2]*[u;X] + D*u + gelu -> gy.
// ---------------------------------------------------------------------------
__global__ __launch_bounds__(256, 4) void fused_conv_kernel(
    const float* __restrict__ u, const unsigned short* __restrict__ A1,
    const unsigned short* __restrict__ A2, const float* __restrict__ lamQ,
    const float* __restrict__ Dv, unsigned short* __restrict__ gy) {
  __shared__ char Sb[16384];  // S^T[bc][n2] u16 (stride 256B), later gy[bc][t] (stride 128B)
  __shared__ char Xb[16384];  // Xprev[bc][n2] u16
  __shared__ char Ub[8192];   // u_bf16 [bc][k] (stride 128B)
  int h = blockIdx.y;
  int bs = blockIdx.x * 2;
  int tid = threadIdx.x;
  int w = tid >> 6, lane = tid & 63, lg = lane >> 4, l15 = lane & 15;

  // ---- stage u -> bf16 LDS (once)
  {
    int row = tid >> 2, k0 = (tid & 3) * 16;
    int b = bs + (row >> 5), c = row & 31;
    const float* up = u + ((size_t)(b * Hh + h)) * Ll + c * 64 + k0;
    uint4 v0 = cvt8q(up), v1 = cvt8q(up + 8);
    int base = row * 128 + k0 * 2;
    int swz = (row & 7) << 4;
    *(uint4*)(Ub + (base ^ swz)) = v0;
    *(uint4*)(Ub + ((base + 16) ^ swz)) = v1;
  }
  // A1 frags (global, no LDS dep)
  bf16x8 a1f[2][2];
#pragma unroll
  for (int i = 0; i < 2; ++i) {
    int row = (2 * w + i) * 16 + l15;
#pragma unroll
    for (int kb = 0; kb < 2; ++kb)
      a1f[i][kb] = *(const bf16x8*)(A1 + ((size_t)h * 128 + row) * 64 + kb * 32 + lg * 8);
  }
  __syncthreads();

  // ---- GEMM1: M=128 (wave w -> mtiles 2w,2w+1), K=64, N=64
#pragma unroll
  for (int ct = 0; ct < 4; ++ct) {
    int bc = ct * 16 + l15;
    bf16x8 bu[2];
#pragma unroll
    for (int kb = 0; kb < 2; ++kb)
      bu[kb] = *(const bf16x8*)(Ub + ((bc * 128 + kb * 64 + lg * 16) ^ ((bc & 7) << 4)));
#pragma unroll
    for (int i = 0; i < 2; ++i) {
      f32x4 acc = {0.f, 0.f, 0.f, 0.f};
      acc = __builtin_amdgcn_mfma_f32_16x16x32_bf16(a1f[i][0], bu[0], acc, 0, 0, 0);
      acc = __builtin_amdgcn_mfma_f32_16x16x32_bf16(a1f[i][1], bu[1], acc, 0, 0, 0);
      int n2q = (2 * w + i) * 16 + lg * 4;
      uint2 pk;
      pk.x = f2b(acc[0]) | ((unsigned)f2b(acc[1]) << 16);
      pk.y = f2b(acc[2]) | ((unsigned)f2b(acc[3]) << 16);
      *(uint2*)(Sb + ((bc * 256 + n2q * 2) ^ ((bc & 7) << 4))) = pk;
    }
  }
  __syncthreads();

  // ---- recurrence over 32 chunks (128 active threads: n x 2 batches)
  {
    int nn = tid & 63, bloc = tid >> 6;
    if (bloc < 2) {
      float lqr = lamQ[h * 128 + 2 * nn], lqi = lamQ[h * 128 + 2 * nn + 1];
      float Xr = 0.f, Xi = 0.f;
      for (int c = 0; c < 32; ++c) {
        int bc = bloc * 32 + c;
        int byte = (bc * 256 + 4 * nn) ^ ((bc & 7) << 4);
        *(unsigned*)(Xb + byte) = (unsigned)f2b(Xr) | ((unsigned)f2b(Xi) << 16);
        unsigned ps = *(const unsigned*)(Sb + byte);
        float Sr = b2f((unsigned short)(ps & 0xFFFF));
        float Si = b2f((unsigned short)(ps >> 16));
        float nXr = lqr * Xr - lqi * Xi + Sr;
        float nXi = lqr * Xi + lqi * Xr + Si;
        Xr = nXr;
        Xi = nXi;
      }
    }
  }
  __syncthreads();

  // ---- GEMM2: M=64 (wave w -> mtile w), K=192, N=64; fused skip+gelu
  bf16x8 a2f[6];
  int rowA = w * 16 + l15;
#pragma unroll
  for (int kb = 0; kb < 6; ++kb)
    a2f[kb] = *(const bf16x8*)(A2 + ((size_t)h * 64 + rowA) * 256 + kb * 32 + lg * 8);
  float Dh = Dv[h];
#pragma unroll
  for (int ct = 0; ct < 4; ++ct) {
    int bc = ct * 16 + l15;
    int b = bs + (bc >> 5), c = bc & 31;
    f32x4 acc = {0.f, 0.f, 0.f, 0.f};
#pragma unroll
    for (int kb = 0; kb < 2; ++kb) {
      bf16x8 bu = *(const bf16x8*)(Ub + ((bc * 128 + kb * 64 + lg * 16) ^ ((bc & 7) << 4)));
      acc = __builtin_amdgcn_mfma_f32_16x16x32_bf16(a2f[kb], bu, acc, 0, 0, 0);
    }
#pragma unroll
    for (int kb = 2; kb < 6; ++kb) {
      bf16x8 bx = *(const bf16x8*)(Xb + ((bc * 256 + ((kb - 2) * 32 + lg * 8) * 2) ^ ((bc & 7) << 4)));
      acc = __builtin_amdgcn_mfma_f32_16x16x32_bf16(a2f[kb], bx, acc, 0, 0, 0);
    }
    int t0 = w * 16 + lg * 4;
    const float* up = u + ((size_t)(b * Hh + h)) * Ll + c * 64;
    float4 uv = *(const float4*)(up + t0);
    const float* uvp = (const float*)&uv;
    unsigned short e[4];
#pragma unroll
    for (int r = 0; r < 4; ++r) {
      float y = fmaf(Dh, uvp[r], acc[r]);
      e[r] = f2b(gelu_f(y));
    }
    uint2 pk;
    pk.x = e[0] | ((unsigned)e[1] << 16);
    pk.y = e[2] | ((unsigned)e[3] << 16);
    *(uint2*)(Sb + ((bc * 128 + t0 * 2) ^ ((bc & 7) << 4))) = pk;
  }
  __syncthreads();

  // ---- coalesced gy copy-out
#pragma unroll
  for (int i = 0; i < 2; ++i) {
    int j = tid + 256 * i;
    int row = j >> 3, t8 = (j & 7) * 8;
    int byte = row * 128 + t8 * 2;
    uint4 v = *(const uint4*)(Sb + (byte ^ ((row & 7) << 4)));
    int b = bs + (row >> 5), c = row & 31;
    *(uint4*)(gy + ((size_t)(b * Hh + h)) * Ll + c * 64 + t8) = v;
  }
}

// ---------------------------------------------------------------------------
// GLU: 512 threads, o-block 128 (wave w -> rows o0+16w, both A and G halves),
// l-tile 128, K=512 in steps of 64 via pair-packed transposed LDS.
// ---------------------------------------------------------------------------
__global__ __launch_bounds__(512, 4) void glu_kernel(
    const unsigned short* __restrict__ gy, const unsigned short* __restrict__ Wbf,
    const float* __restrict__ bias, float* __restrict__ out) {
  __shared__ unsigned int Pl[128 * 32];  // [row l][pair p], swizzled
  int b = blockIdx.z;
  int o0 = blockIdx.y * 128;
  int l0 = blockIdx.x * 128;
  int tid = threadIdx.x;
  int w = tid >> 6, lane = tid & 63, lg = lane >> 4, l15 = lane & 15;
  f32x4 accA[8], accG[8];
#pragma unroll
  for (int ct = 0; ct < 8; ++ct) {
    accA[ct] = (f32x4){0.f, 0.f, 0.f, 0.f};
    accG[ct] = (f32x4){0.f, 0.f, 0.f, 0.f};
  }
  int aro = o0 + w * 16 + l15;
  const unsigned short* wa = Wbf + (size_t)aro * 512;
  const unsigned short* wg = Wbf + (size_t)(Hh + aro) * 512;
  for (int h0 = 0; h0 < Hh; h0 += 64) {
    // stage gy tile (single pass with 512 threads)
    {
      int p = tid >> 4, cg = tid & 15;
      const unsigned short* g0 = gy + ((size_t)(b * Hh) + h0 + 2 * p) * Ll + l0 + cg * 8;
      BF8 r0, r1;
      r0.q = *(const uint4*)g0;
      r1.q = *(const uint4*)(g0 + Ll);
#pragma unroll
      for (int j = 0; j < 8; ++j) {
        int row = cg * 8 + j;
        int slot = (p >> 2) ^ ((row ^ (row >> 3)) & 7);
        Pl[row * 32 + slot * 4 + (p & 3)] =
            (unsigned)r0.us[j] | ((unsigned)r1.us[j] << 16);
      }
    }
    __syncthreads();
    bf16x8 aA[2], aG[2];
#pragma unroll
    for (int kb = 0; kb < 2; ++kb) {
      aA[kb] = *(const bf16x8*)(wa + h0 + kb * 32 + lg * 8);
      aG[kb] = *(const bf16x8*)(wg + h0 + kb * 32 + lg * 8);
    }
#pragma unroll
    for (int ct = 0; ct < 8; ++ct) {
      int rowB = ct * 16 + l15;
      int sw = (rowB ^ (rowB >> 3)) & 7;
#pragma unroll
      for (int kb = 0; kb < 2; ++kb) {
        int slot = (kb * 4 + lg) ^ sw;
        bf16x8 bv = *(const bf16x8*)((const char*)Pl + rowB * 128 + slot * 16);
        accA[ct] = __builtin_amdgcn_mfma_f32_16x16x32_bf16(aA[kb], bv, accA[ct], 0, 0, 0);
        accG[ct] = __builtin_amdgcn_mfma_f32_16x16x32_bf16(aG[kb], bv, accG[ct], 0, 0, 0);
      }
    }
    __syncthreads();
  }
  // epilogue
#pragma unroll
  for (int ct = 0; ct < 8; ++ct) {
    int col = l0 + ct * 16 + l15;
#pragma unroll
    for (int r = 0; r < 4; ++r) {
      int o = o0 + w * 16 + lg * 4 + r;
      float a = accA[ct][r] + bias[o];
      float g = accG[ct][r] + bias[Hh + o];
      out[((size_t)(b * Hh + o)) * Ll + col] = a * (1.0f / (1.0f + __expf(-g)));
    }
  }
}

// ---------------------------------------------------------------------------
extern "C" void kernel_launch(void* const* d_in, const int* in_sizes, int n_in,
                              void* d_out, int out_size, void* d_ws,
                              size_t ws_size, hipStream_t stream) {
  const float* u      = (const float*)d_in[0];
  const float* C_ri   = (const float*)d_in[1];
  const float* log_dt = (const float*)d_in[2];
  const float* Dv     = (const float*)d_in[3];
  const float* W      = (const float*)d_in[4];
  const float* bias   = (const float*)d_in[5];
  const float* A_ri   = (const float*)d_in[6];
  float* out = (float*)d_out;

  char* ws = (char*)d_ws;
  unsigned short* A1   = (unsigned short*)ws;                          // 8 MB
  unsigned short* A2   = (unsigned short*)(ws + 8388608);              // 16 MB
  float*          lamQ = (float*)(ws + 25165824);                      // 256 KB
  unsigned short* Wbf  = (unsigned short*)(ws + 25427968);             // 1 MB
  unsigned short* gy   = (unsigned short*)(ws + 26476544);             // 16 MB

  prep_kernel<<<Hh, 64, 0, stream>>>(C_ri, log_dt, A_ri, A1, A2, lamQ);
  wcvt_kernel<<<(2 * Hh * Hh) / (256 * 8), 256, 0, stream>>>(W, Wbf);
  fused_conv_kernel<<<dim3(4, Hh), 256, 0, stream>>>(u, A1, A2, lamQ, Dv, gy);
  glu_kernel<<<dim3(Ll / 128, 4, Bb), 512, 0, stream>>>(gy, Wbf, bias, out);
}